// Round 1
// baseline (4894.653 us; speedup 1.0000x reference)
//
#include <hip/hip_runtime.h>
#include <cstddef>
#include <cstdint>

#define N_NODES 5120
#define E_EDGES 163840
#define F 256
#define TSTEPS 24
#define KD 1024   // GEMM K  = 4*256
#define ND 1024   // GEMM N  = 4*256 (gates I,F,T,O)
#define XROWSTRIDE 6144  // T*F = 24*256

// ---------------- graph preprocessing ----------------

__global__ void deg_kernel(const float* __restrict__ ew, const int* __restrict__ src,
                           float* __restrict__ deg) {
    int e = blockIdx.x * 256 + threadIdx.x;
    if (e < E_EDGES) atomicAdd(&deg[src[e]], ew[e]);
}

__global__ void dis_kernel(float* __restrict__ deg) {
    int n = blockIdx.x * 256 + threadIdx.x;
    if (n < N_NODES) {
        float d = deg[n];
        deg[n] = d > 0.f ? rsqrtf(d) : 0.f;
    }
}

__global__ void count_kernel(const int* __restrict__ dst, int* __restrict__ cnt) {
    int e = blockIdx.x * 256 + threadIdx.x;
    if (e < E_EDGES) atomicAdd(&cnt[dst[e]], 1);
}

// one block, 256 threads, 20 counts each (N_NODES = 256*20)
__global__ void scan_kernel(const int* __restrict__ cnt, int* __restrict__ row_ptr) {
    __shared__ int s[256];
    int tid = threadIdx.x;
    int base = tid * 20;
    int local[20];
    int sum = 0;
    #pragma unroll
    for (int i = 0; i < 20; i++) { local[i] = sum; sum += cnt[base + i]; }
    s[tid] = sum;
    __syncthreads();
    for (int off = 1; off < 256; off <<= 1) {
        int v = (tid >= off) ? s[tid - off] : 0;
        __syncthreads();
        s[tid] += v;
        __syncthreads();
    }
    int offset = (tid == 0) ? 0 : s[tid - 1];
    #pragma unroll
    for (int i = 0; i < 20; i++) row_ptr[base + i] = offset + local[i];
    if (tid == 0) row_ptr[N_NODES] = E_EDGES;
}

__global__ void fill_csr(const int* __restrict__ src, const int* __restrict__ dst,
                         const float* __restrict__ ew, const float* __restrict__ dis,
                         const int* __restrict__ row_ptr, int* __restrict__ cursor,
                         int* __restrict__ csr_src, float* __restrict__ csr_w) {
    int e = blockIdx.x * 256 + threadIdx.x;
    if (e >= E_EDGES) return;
    int s = src[e], d = dst[e];
    int pos = row_ptr[d] + atomicAdd(&cursor[d], 1);
    csr_src[pos] = s;
    // w_hat = (2/lambda_max) * (-dis[src]*w*dis[dst]); lambda_max=2 -> factor 1
    csr_w[pos] = -dis[s] * ew[e] * dis[d];
}

// pack [Ws_g | theta_g0 | theta_g1 | theta_g2] -> Wcat[1024][1024], col block g = gate
__global__ void build_wcat(const float* __restrict__ Ws, const float* __restrict__ thetas,
                           float* __restrict__ Wcat) {
    int idx = blockIdx.x * 256 + threadIdx.x;
    if (idx >= 1024 * 1024) return;
    int r = idx >> 10, c = idx & 1023;
    int g = c >> 8, j = c & 255;
    float v;
    if (r < 256) {
        v = Ws[(g * 256 + r) * 256 + j];
    } else {
        int k = (r >> 8) - 1;          // 0..2
        int rr = r & 255;
        v = thetas[((g * 3 + k) * 256 + rr) * 256 + j];
    }
    Wcat[idx] = v;
}

// ---------------- per-timestep kernels ----------------

// out[n,f] = scale * sum_e w[e]*xin[src[e],f]  (- sub[n,f] if sub)
__global__ void prop_kernel(const float* __restrict__ xin, const float* __restrict__ sub,
                            float scale, const int* __restrict__ row_ptr,
                            const int* __restrict__ csr_src, const float* __restrict__ csr_w,
                            float* __restrict__ out) {
    __shared__ int s_src[256];
    __shared__ float s_w[256];
    int n = blockIdx.x;
    int tid = threadIdx.x;
    int start = row_ptr[n], end = row_ptr[n + 1];
    float acc = 0.f;
    for (int base = start; base < end; base += 256) {
        int chunk = min(256, end - base);
        if (tid < chunk) {
            s_src[tid] = csr_src[base + tid];
            s_w[tid] = csr_w[base + tid];
        }
        __syncthreads();
        for (int i = 0; i < chunk; i++)
            acc += s_w[i] * xin[(size_t)s_src[i] * F + tid];
        __syncthreads();
    }
    float r = scale * acc;
    size_t o = (size_t)n * F + tid;
    if (sub) r -= sub[o];
    out[o] = r;
}

// C[M=5120, N=1024] = A[M, 1024] @ Wcat[1024, 1024]
// A columns: [0:256)=X_t (stride 6144), [256:512)=H, [512:768)=Tx1, [768:1024)=Tx2
#define BM 128
#define BN 64
#define BK 16

__global__ __launch_bounds__(256) void gemm_kernel(
        const float* __restrict__ X, const float* __restrict__ H,
        const float* __restrict__ Tx1, const float* __restrict__ Tx2,
        const float* __restrict__ Wcat, int t, float* __restrict__ G) {
    __shared__ float As[BK][BM + 4];
    __shared__ float Bs[BK][BN + 4];
    int tid = threadIdx.x;
    int m0 = blockIdx.x * BM;
    int n0 = blockIdx.y * BN;

    int tm = tid >> 4;        // 0..15 -> rows tm*8 .. tm*8+7
    int tn = tid & 15;        // 0..15 -> cols tn*4 .. tn*4+3

    int la_k = (tid & 3) * 4; // 0,4,8,12
    int la_m = tid >> 2;      // 0..63  (plus +64 second pass)
    int lb_n = (tid & 15) * 4;
    int lb_k = tid >> 4;

    float acc[8][4] = {};

    for (int k0 = 0; k0 < KD; k0 += BK) {
        int seg = k0 >> 8;
        int jb = k0 & 255;
        const float* aptr;
        int astride;
        if (seg == 0)      { aptr = X + (size_t)t * 256 + jb; astride = XROWSTRIDE; }
        else if (seg == 1) { aptr = H + jb;   astride = F; }
        else if (seg == 2) { aptr = Tx1 + jb; astride = F; }
        else               { aptr = Tx2 + jb; astride = F; }

        #pragma unroll
        for (int p = 0; p < 2; p++) {
            int m = la_m + p * 64;
            float4 v = *(const float4*)(aptr + (size_t)(m0 + m) * astride + la_k);
            As[la_k + 0][m] = v.x;
            As[la_k + 1][m] = v.y;
            As[la_k + 2][m] = v.z;
            As[la_k + 3][m] = v.w;
        }
        *(float4*)&Bs[lb_k][lb_n] =
            *(const float4*)(Wcat + (size_t)(k0 + lb_k) * ND + n0 + lb_n);
        __syncthreads();

        #pragma unroll
        for (int kk = 0; kk < BK; kk++) {
            float a[8], b[4];
            #pragma unroll
            for (int i = 0; i < 8; i++) a[i] = As[kk][tm * 8 + i];
            #pragma unroll
            for (int j = 0; j < 4; j++) b[j] = Bs[kk][tn * 4 + j];
            #pragma unroll
            for (int i = 0; i < 8; i++)
                #pragma unroll
                for (int j = 0; j < 4; j++)
                    acc[i][j] += a[i] * b[j];
        }
        __syncthreads();
    }

    #pragma unroll
    for (int i = 0; i < 8; i++) {
        size_t m = m0 + tm * 8 + i;
        #pragma unroll
        for (int j = 0; j < 4; j++)
            G[m * ND + n0 + tn * 4 + j] = acc[i][j];
    }
}

__global__ void lstm_kernel(const float* __restrict__ G, const float* __restrict__ bs,
                            const float* __restrict__ cbs, float* __restrict__ H,
                            float* __restrict__ C) {
    int i = blockIdx.x * 256 + threadIdx.x;
    if (i >= N_NODES * F) return;
    int n = i >> 8, j = i & 255;
    const float* g = G + (size_t)n * ND;
    float pi = g[j]       + bs[j]       + cbs[j];
    float pf = g[256 + j] + bs[256 + j] + cbs[256 + j];
    float pt = g[512 + j] + bs[512 + j] + cbs[512 + j];
    float po = g[768 + j] + bs[768 + j] + cbs[768 + j];
    float I  = 1.f / (1.f + expf(-pi));
    float Fg = 1.f / (1.f + expf(-pf));
    float Tc = tanhf(pt);
    float O  = 1.f / (1.f + expf(-po));
    float c  = Fg * C[i] + I * Tc;
    C[i] = c;
    H[i] = O * tanhf(c);
}

// ---------------- launch ----------------

extern "C" void kernel_launch(void* const* d_in, const int* in_sizes, int n_in,
                              void* d_out, int out_size, void* d_ws, size_t ws_size,
                              hipStream_t stream) {
    const float* X   = (const float*)d_in[0];
    const float* ew  = (const float*)d_in[1];
    const float* Ws  = (const float*)d_in[2];
    const float* bs  = (const float*)d_in[3];
    const float* th  = (const float*)d_in[4];
    const float* cbs = (const float*)d_in[5];
    const int*   ei  = (const int*)d_in[6];
    const int* src = ei;
    const int* dst = ei + E_EDGES;

    float* H = (float*)d_out;               // N*F
    float* C = H + (size_t)N_NODES * F;     // N*F

    char* w = (char*)d_ws;
    size_t off = 0;
    auto alloc = [&](size_t bytes) {
        void* p = w + off;
        off += (bytes + 255) & ~(size_t)255;
        return p;
    };
    float* deg     = (float*)alloc(N_NODES * 4);
    int*   cnt     = (int*)  alloc(N_NODES * 4);
    int*   cursor  = (int*)  alloc(N_NODES * 4);
    int*   row_ptr = (int*)  alloc((N_NODES + 1) * 4);
    int*   csr_src = (int*)  alloc(E_EDGES * 4);
    float* csr_w   = (float*)alloc(E_EDGES * 4);
    float* Tx1     = (float*)alloc((size_t)N_NODES * F * 4);
    float* Tx2     = (float*)alloc((size_t)N_NODES * F * 4);
    float* G       = (float*)alloc((size_t)N_NODES * ND * 4);
    float* Wcat    = (float*)alloc((size_t)KD * ND * 4);

    // init
    hipMemsetAsync(d_out, 0, (size_t)2 * N_NODES * F * 4, stream);
    hipMemsetAsync(deg, 0, N_NODES * 4, stream);
    hipMemsetAsync(cnt, 0, N_NODES * 4, stream);
    hipMemsetAsync(cursor, 0, N_NODES * 4, stream);

    int eb = E_EDGES / 256;
    deg_kernel<<<eb, 256, 0, stream>>>(ew, src, deg);
    dis_kernel<<<N_NODES / 256, 256, 0, stream>>>(deg);
    count_kernel<<<eb, 256, 0, stream>>>(dst, cnt);
    scan_kernel<<<1, 256, 0, stream>>>(cnt, row_ptr);
    fill_csr<<<eb, 256, 0, stream>>>(src, dst, ew, deg, row_ptr, cursor, csr_src, csr_w);
    build_wcat<<<(1024 * 1024) / 256, 256, 0, stream>>>(Ws, th, Wcat);

    dim3 ggrid(N_NODES / BM, ND / BN);
    for (int t = 0; t < TSTEPS; t++) {
        prop_kernel<<<N_NODES, 256, 0, stream>>>(H, nullptr, 1.f, row_ptr, csr_src, csr_w, Tx1);
        prop_kernel<<<N_NODES, 256, 0, stream>>>(Tx1, H, 2.f, row_ptr, csr_src, csr_w, Tx2);
        gemm_kernel<<<ggrid, 256, 0, stream>>>(X, H, Tx1, Tx2, Wcat, t, G);
        lstm_kernel<<<(N_NODES * F) / 256, 256, 0, stream>>>(G, bs, cbs, H, C);
    }
}

// Round 2
// 1534.599 us; speedup vs baseline: 3.1895x; 3.1895x over previous
//
#include <hip/hip_runtime.h>
#include <cstddef>
#include <cstdint>

#define N_NODES 5120
#define E_EDGES 163840
#define F 256
#define TSTEPS 24
#define ND 1024          // GEMM N = 4*256 (gates I,F,T,O)
#define XROWSTRIDE 6144  // T*F

typedef unsigned short u16;
typedef unsigned int u32;
typedef __bf16 bf16x8 __attribute__((ext_vector_type(8)));
typedef float f32x4 __attribute__((ext_vector_type(4)));

__device__ __forceinline__ u16 f2bf(float f) {
    u32 u = __float_as_uint(f);
    u = (u + 0x7FFFu + ((u >> 16) & 1u)) >> 16;  // round-to-nearest-even
    return (u16)u;
}
__device__ __forceinline__ float bf2f(u16 h) {
    return __uint_as_float((u32)h << 16);
}

// ---------------- graph preprocessing ----------------

__global__ void deg_kernel(const float* __restrict__ ew, const int* __restrict__ src,
                           float* __restrict__ deg) {
    int e = blockIdx.x * 256 + threadIdx.x;
    if (e < E_EDGES) atomicAdd(&deg[src[e]], ew[e]);
}

__global__ void dis_kernel(float* __restrict__ deg) {
    int n = blockIdx.x * 256 + threadIdx.x;
    if (n < N_NODES) {
        float d = deg[n];
        deg[n] = d > 0.f ? rsqrtf(d) : 0.f;
    }
}

__global__ void count_kernel(const int* __restrict__ dst, int* __restrict__ cnt) {
    int e = blockIdx.x * 256 + threadIdx.x;
    if (e < E_EDGES) atomicAdd(&cnt[dst[e]], 1);
}

// one block, 256 threads, 20 counts each (N_NODES = 256*20)
__global__ void scan_kernel(const int* __restrict__ cnt, int* __restrict__ row_ptr) {
    __shared__ int s[256];
    int tid = threadIdx.x;
    int base = tid * 20;
    int local[20];
    int sum = 0;
    #pragma unroll
    for (int i = 0; i < 20; i++) { local[i] = sum; sum += cnt[base + i]; }
    s[tid] = sum;
    __syncthreads();
    for (int off = 1; off < 256; off <<= 1) {
        int v = (tid >= off) ? s[tid - off] : 0;
        __syncthreads();
        s[tid] += v;
        __syncthreads();
    }
    int offset = (tid == 0) ? 0 : s[tid - 1];
    #pragma unroll
    for (int i = 0; i < 20; i++) row_ptr[base + i] = offset + local[i];
    if (tid == 0) row_ptr[N_NODES] = E_EDGES;
}

__global__ void fill_csr(const int* __restrict__ src, const int* __restrict__ dst,
                         const float* __restrict__ ew, const float* __restrict__ dis,
                         const int* __restrict__ row_ptr, int* __restrict__ cursor,
                         int* __restrict__ csr_src, float* __restrict__ csr_w) {
    int e = blockIdx.x * 256 + threadIdx.x;
    if (e >= E_EDGES) return;
    int s = src[e], d = dst[e];
    int pos = row_ptr[d] + atomicAdd(&cursor[d], 1);
    csr_src[pos] = s;
    // w_hat = (2/lambda_max)*(-dis[src]*w*dis[dst]); lambda_max=2 -> factor 1
    csr_w[pos] = -dis[s] * ew[e] * dis[d];
}

// WcatT[c][k] (bf16, c = output col = gate*256+j, k contiguous) = Wcat[k][c]
__global__ void build_wcatT(const float* __restrict__ Ws, const float* __restrict__ thetas,
                            u16* __restrict__ WT) {
    int idx = blockIdx.x * 256 + threadIdx.x;
    if (idx >= 1024 * 1024) return;
    int c = idx >> 10, k = idx & 1023;
    int g = c >> 8, j = c & 255;
    float v;
    if (k < 256) {
        v = Ws[(g * 256 + k) * 256 + j];
    } else {
        int kc = (k >> 8) - 1;  // 0..2
        int rr = k & 255;
        v = thetas[((g * 3 + kc) * 256 + rr) * 256 + j];
    }
    WT[idx] = f2bf(v);
}

// ---------------- per-timestep kernels ----------------

// out_bf[n,f] = bf16( scale * sum_e w[e]*xin[src[e],f]  - (sub? sub[n,f] : 0) )
// optionally also converts X_t slice to bf16 (fused X staging)
__global__ void prop_kernel(const u16* __restrict__ xin, const u16* __restrict__ sub,
                            float scale, const int* __restrict__ row_ptr,
                            const int* __restrict__ csr_src, const float* __restrict__ csr_w,
                            u16* __restrict__ out_bf,
                            const float* __restrict__ X, int t, u16* __restrict__ xt_out) {
    __shared__ int s_src[256];
    __shared__ float s_w[256];
    int n = blockIdx.x;
    int tid = threadIdx.x;
    int start = row_ptr[n], end = row_ptr[n + 1];
    float acc = 0.f;
    for (int base = start; base < end; base += 256) {
        int chunk = min(256, end - base);
        if (tid < chunk) {
            s_src[tid] = csr_src[base + tid];
            s_w[tid] = csr_w[base + tid];
        }
        __syncthreads();
        for (int i = 0; i < chunk; i++)
            acc += s_w[i] * bf2f(xin[(size_t)s_src[i] * F + tid]);
        __syncthreads();
    }
    size_t o = (size_t)n * F + tid;
    float r = scale * acc;
    if (sub) r -= bf2f(sub[o]);
    out_bf[o] = f2bf(r);
    if (xt_out) xt_out[o] = f2bf(X[(size_t)n * XROWSTRIDE + (size_t)t * F + tid]);
}

// ---------------- bf16 MFMA GEMM: G[5120,1024] = A[5120,1024] @ W[1024,1024] ----------------
// A = [Xt | H | Tx1 | Tx2] (4 bf16 buffers, row stride 256).  WT is B^T (n-major, k-contig).
#define GBM 128
#define GBN 128
#define GBK 64

__global__ __launch_bounds__(256) void mfma_gemm(
        const u16* __restrict__ Xt, const u16* __restrict__ Hb,
        const u16* __restrict__ T1, const u16* __restrict__ T2,
        const u16* __restrict__ WT, float* __restrict__ G) {
    __shared__ alignas(16) u16 As[GBM * GBK];
    __shared__ alignas(16) u16 Bs[GBN * GBK];
    int tid = threadIdx.x;
    int w = tid >> 6, l = tid & 63;
    int m0 = blockIdx.x * GBM, n0 = blockIdx.y * GBN;
    int wm = (w >> 1) * 64, wn = (w & 1) * 64;

    // staging geometry: chunk c covers LDS rows [c*8, c*8+8); lane l -> row c*8 + l/8.
    // T2 swizzle, rule #21: linear LDS dest + inverse-swizzled SOURCE col + swizzled READ.
    int srow = l >> 3;                // row-within-8 = (row & 7)
    int scol = 8 * ((l & 7) ^ srow);  // source elem col for this lane's 16B

    f32x4 acc[4][4] = {};

    for (int k0 = 0; k0 < 1024; k0 += GBK) {
        int seg = k0 >> 8;
        const u16* ab = (seg == 0) ? Xt : (seg == 1) ? Hb : (seg == 2) ? T1 : T2;
        ab += (k0 & 255);
        const u16* bb = WT + k0;
        #pragma unroll
        for (int i = 0; i < 4; i++) {
            int c = i * 4 + w;
            int row = c * 8 + srow;
            __builtin_amdgcn_global_load_lds(
                (const __attribute__((address_space(1))) u32*)(ab + (size_t)(m0 + row) * F + scol),
                (__attribute__((address_space(3))) u32*)(As + c * 512), 16, 0, 0);
            __builtin_amdgcn_global_load_lds(
                (const __attribute__((address_space(1))) u32*)(bb + (size_t)(n0 + row) * 1024 + scol),
                (__attribute__((address_space(3))) u32*)(Bs + c * 512), 16, 0, 0);
        }
        __syncthreads();
        #pragma unroll
        for (int kk = 0; kk < 2; kk++) {
            int kr = kk * 32 + (l >> 4) * 8;
            bf16x8 af[4], bfr[4];
            #pragma unroll
            for (int mf = 0; mf < 4; mf++) {
                int r = wm + mf * 16 + (l & 15);
                af[mf] = *(const bf16x8*)(As + r * GBK + (kr ^ ((r & 7) << 3)));
            }
            #pragma unroll
            for (int nf = 0; nf < 4; nf++) {
                int r = wn + nf * 16 + (l & 15);
                bfr[nf] = *(const bf16x8*)(Bs + r * GBK + (kr ^ ((r & 7) << 3)));
            }
            #pragma unroll
            for (int mf = 0; mf < 4; mf++)
                #pragma unroll
                for (int nf = 0; nf < 4; nf++)
                    acc[mf][nf] = __builtin_amdgcn_mfma_f32_16x16x32_bf16(
                        af[mf], bfr[nf], acc[mf][nf], 0, 0, 0);
        }
        __syncthreads();
    }

    // C/D layout: col = lane&15, row = (lane>>4)*4 + reg   [m89-verified]
    int cr = (l >> 4) * 4, cc = l & 15;
    #pragma unroll
    for (int mf = 0; mf < 4; mf++) {
        #pragma unroll
        for (int r = 0; r < 4; r++) {
            size_t gr = (size_t)(m0 + wm + mf * 16 + cr + r) * ND;
            #pragma unroll
            for (int nf = 0; nf < 4; nf++)
                G[gr + n0 + wn + nf * 16 + cc] = acc[mf][nf][r];
        }
    }
}

// ---------------- LSTM pointwise (vectorized x4), emits H fp32 + H bf16 ----------------

__global__ void lstm_kernel(const float* __restrict__ G, const float* __restrict__ bs,
                            const float* __restrict__ cbs, float* __restrict__ H,
                            float* __restrict__ C, u16* __restrict__ Hb) {
    int idx = blockIdx.x * 256 + threadIdx.x;  // N*F/4 threads
    if (idx >= N_NODES * F / 4) return;
    int n = idx >> 6;
    int j = (idx & 63) * 4;
    const float* g = G + (size_t)n * ND;
    float4 gi = *(const float4*)(g + j);
    float4 gf = *(const float4*)(g + 256 + j);
    float4 gt = *(const float4*)(g + 512 + j);
    float4 go = *(const float4*)(g + 768 + j);
    float4 b0 = *(const float4*)(bs + j);
    float4 b1 = *(const float4*)(bs + 256 + j);
    float4 b2 = *(const float4*)(bs + 512 + j);
    float4 b3 = *(const float4*)(bs + 768 + j);
    float4 c0 = *(const float4*)(cbs + j);
    float4 c1 = *(const float4*)(cbs + 256 + j);
    float4 c2 = *(const float4*)(cbs + 512 + j);
    float4 c3 = *(const float4*)(cbs + 768 + j);
    size_t o = (size_t)n * F + j;
    float4 Cv = *(const float4*)(C + o);
    float hv[4], cv[4];
    float gia[4] = {gi.x, gi.y, gi.z, gi.w}, gfa[4] = {gf.x, gf.y, gf.z, gf.w};
    float gta[4] = {gt.x, gt.y, gt.z, gt.w}, goa[4] = {go.x, go.y, go.z, go.w};
    float b0a[4] = {b0.x, b0.y, b0.z, b0.w}, b1a[4] = {b1.x, b1.y, b1.z, b1.w};
    float b2a[4] = {b2.x, b2.y, b2.z, b2.w}, b3a[4] = {b3.x, b3.y, b3.z, b3.w};
    float c0a[4] = {c0.x, c0.y, c0.z, c0.w}, c1a[4] = {c1.x, c1.y, c1.z, c1.w};
    float c2a[4] = {c2.x, c2.y, c2.z, c2.w}, c3a[4] = {c3.x, c3.y, c3.z, c3.w};
    float Ca[4] = {Cv.x, Cv.y, Cv.z, Cv.w};
    #pragma unroll
    for (int q = 0; q < 4; q++) {
        float I  = 1.f / (1.f + expf(-(gia[q] + b0a[q] + c0a[q])));
        float Fg = 1.f / (1.f + expf(-(gfa[q] + b1a[q] + c1a[q])));
        float Tc = tanhf(gta[q] + b2a[q] + c2a[q]);
        float O  = 1.f / (1.f + expf(-(goa[q] + b3a[q] + c3a[q])));
        float c  = Fg * Ca[q] + I * Tc;
        cv[q] = c;
        hv[q] = O * tanhf(c);
    }
    *(float4*)(C + o) = make_float4(cv[0], cv[1], cv[2], cv[3]);
    *(float4*)(H + o) = make_float4(hv[0], hv[1], hv[2], hv[3]);
    u32 lo = f2bf(hv[0]) | ((u32)f2bf(hv[1]) << 16);
    u32 hi = f2bf(hv[2]) | ((u32)f2bf(hv[3]) << 16);
    *(uint2*)(Hb + o) = make_uint2(lo, hi);
}

// ---------------- launch ----------------

extern "C" void kernel_launch(void* const* d_in, const int* in_sizes, int n_in,
                              void* d_out, int out_size, void* d_ws, size_t ws_size,
                              hipStream_t stream) {
    const float* X   = (const float*)d_in[0];
    const float* ew  = (const float*)d_in[1];
    const float* Ws  = (const float*)d_in[2];
    const float* bs  = (const float*)d_in[3];
    const float* th  = (const float*)d_in[4];
    const float* cbs = (const float*)d_in[5];
    const int*   ei  = (const int*)d_in[6];
    const int* src = ei;
    const int* dst = ei + E_EDGES;

    float* H = (float*)d_out;               // N*F
    float* C = H + (size_t)N_NODES * F;     // N*F

    char* w = (char*)d_ws;
    size_t off = 0;
    auto alloc = [&](size_t bytes) {
        void* p = w + off;
        off += (bytes + 255) & ~(size_t)255;
        return p;
    };
    float* deg     = (float*)alloc(N_NODES * 4);
    int*   cnt     = (int*)  alloc(N_NODES * 4);
    int*   cursor  = (int*)  alloc(N_NODES * 4);
    int*   row_ptr = (int*)  alloc((N_NODES + 1) * 4);
    int*   csr_src = (int*)  alloc(E_EDGES * 4);
    float* csr_w   = (float*)alloc(E_EDGES * 4);
    u16*   WT      = (u16*)  alloc((size_t)1024 * 1024 * 2);
    u16*   Xtbf    = (u16*)  alloc((size_t)N_NODES * F * 2);
    u16*   Hbf     = (u16*)  alloc((size_t)N_NODES * F * 2);
    u16*   Tx1bf   = (u16*)  alloc((size_t)N_NODES * F * 2);
    u16*   Tx2bf   = (u16*)  alloc((size_t)N_NODES * F * 2);
    float* G       = (float*)alloc((size_t)N_NODES * ND * 4);

    hipMemsetAsync(d_out, 0, (size_t)2 * N_NODES * F * 4, stream);
    hipMemsetAsync(Hbf, 0, (size_t)N_NODES * F * 2, stream);
    hipMemsetAsync(deg, 0, N_NODES * 4, stream);
    hipMemsetAsync(cnt, 0, N_NODES * 4, stream);
    hipMemsetAsync(cursor, 0, N_NODES * 4, stream);

    int eb = E_EDGES / 256;
    deg_kernel<<<eb, 256, 0, stream>>>(ew, src, deg);
    dis_kernel<<<N_NODES / 256, 256, 0, stream>>>(deg);
    count_kernel<<<eb, 256, 0, stream>>>(dst, cnt);
    scan_kernel<<<1, 256, 0, stream>>>(cnt, row_ptr);
    fill_csr<<<eb, 256, 0, stream>>>(src, dst, ew, deg, row_ptr, cursor, csr_src, csr_w);
    build_wcatT<<<(1024 * 1024) / 256, 256, 0, stream>>>(Ws, th, WT);

    dim3 ggrid(N_NODES / GBM, ND / GBN);
    for (int t = 0; t < TSTEPS; t++) {
        // Tx1 = L_hat @ H   (+ fused X_t -> bf16 conversion)
        prop_kernel<<<N_NODES, 256, 0, stream>>>(Hbf, nullptr, 1.f, row_ptr, csr_src, csr_w,
                                                 Tx1bf, X, t, Xtbf);
        // Tx2 = 2 * (L_hat @ Tx1) - H
        prop_kernel<<<N_NODES, 256, 0, stream>>>(Tx1bf, Hbf, 2.f, row_ptr, csr_src, csr_w,
                                                 Tx2bf, nullptr, 0, nullptr);
        mfma_gemm<<<ggrid, 256, 0, stream>>>(Xtbf, Hbf, Tx1bf, Tx2bf, WT, G);
        lstm_kernel<<<(N_NODES * F / 4 + 255) / 256, 256, 0, stream>>>(G, bs, cbs, H, C, Hbf);
    }
}

// Round 3
// 1180.527 us; speedup vs baseline: 4.1462x; 1.2999x over previous
//
#include <hip/hip_runtime.h>
#include <cstddef>
#include <cstdint>

#define N_NODES 5120
#define E_EDGES 163840
#define F 256
#define TSTEPS 24
#define ND 1024          // GEMM N = 4*256 (gates, column-permuted)
#define XROWSTRIDE 6144  // T*F

typedef unsigned short u16;
typedef unsigned int u32;
typedef __bf16 bf16x8 __attribute__((ext_vector_type(8)));
typedef float f32x4 __attribute__((ext_vector_type(4)));

__device__ __forceinline__ u16 f2bf(float f) {
    u32 u = __float_as_uint(f);
    u = (u + 0x7FFFu + ((u >> 16) & 1u)) >> 16;  // round-to-nearest-even
    return (u16)u;
}
__device__ __forceinline__ float bf2f(u16 h) {
    return __uint_as_float((u32)h << 16);
}
__device__ __forceinline__ float fsigmoid(float x) {
    return 1.f / (1.f + __expf(-x));
}
__device__ __forceinline__ float ftanh(float x) {
    // tanh(x) = 1 - 2/(exp(2x)+1); saturates correctly for |x| large
    return 1.f - 2.f / (__expf(2.f * x) + 1.f);
}

// ---------------- graph preprocessing ----------------

__global__ void deg_kernel(const float* __restrict__ ew, const int* __restrict__ src,
                           float* __restrict__ deg) {
    int e = blockIdx.x * 256 + threadIdx.x;
    if (e < E_EDGES) atomicAdd(&deg[src[e]], ew[e]);
}

__global__ void dis_kernel(float* __restrict__ deg) {
    int n = blockIdx.x * 256 + threadIdx.x;
    if (n < N_NODES) {
        float d = deg[n];
        deg[n] = d > 0.f ? rsqrtf(d) : 0.f;
    }
}

__global__ void count_kernel(const int* __restrict__ dst, int* __restrict__ cnt) {
    int e = blockIdx.x * 256 + threadIdx.x;
    if (e < E_EDGES) atomicAdd(&cnt[dst[e]], 1);
}

// one block, 256 threads, 20 counts each (N_NODES = 256*20)
__global__ void scan_kernel(const int* __restrict__ cnt, int* __restrict__ row_ptr) {
    __shared__ int s[256];
    int tid = threadIdx.x;
    int base = tid * 20;
    int local[20];
    int sum = 0;
    #pragma unroll
    for (int i = 0; i < 20; i++) { local[i] = sum; sum += cnt[base + i]; }
    s[tid] = sum;
    __syncthreads();
    for (int off = 1; off < 256; off <<= 1) {
        int v = (tid >= off) ? s[tid - off] : 0;
        __syncthreads();
        s[tid] += v;
        __syncthreads();
    }
    int offset = (tid == 0) ? 0 : s[tid - 1];
    #pragma unroll
    for (int i = 0; i < 20; i++) row_ptr[base + i] = offset + local[i];
    if (tid == 0) row_ptr[N_NODES] = E_EDGES;
}

__global__ void fill_csr(const int* __restrict__ src, const int* __restrict__ dst,
                         const float* __restrict__ ew, const float* __restrict__ dis,
                         const int* __restrict__ row_ptr, int* __restrict__ cursor,
                         int* __restrict__ csr_src, float* __restrict__ csr_w) {
    int e = blockIdx.x * 256 + threadIdx.x;
    if (e >= E_EDGES) return;
    int s = src[e], d = dst[e];
    int pos = row_ptr[d] + atomicAdd(&cursor[d], 1);
    csr_src[pos] = s;
    // w_hat = (2/lambda_max)*(-dis[src]*w*dis[dst]); lambda_max=2 -> factor 1
    csr_w[pos] = -dis[s] * ew[e] * dis[d];
}

// Column permutation: col'(g, j) = (j>>4)*64 + g*16 + (j&15).
// Inverse: g = (c>>4)&3, j = (c>>6)*16 + (c&15).
// WT[c'][k] (bf16, k contiguous) = Wcat[k][g*256+j]
__global__ void build_wcatT(const float* __restrict__ Ws, const float* __restrict__ thetas,
                            u16* __restrict__ WT) {
    int idx = blockIdx.x * 256 + threadIdx.x;
    if (idx >= 1024 * 1024) return;
    int c = idx >> 10, k = idx & 1023;
    int g = (c >> 4) & 3;
    int j = (c >> 6) * 16 + (c & 15);
    float v;
    if (k < 256) {
        v = Ws[(g * 256 + k) * 256 + j];
    } else {
        int kc = (k >> 8) - 1;  // 0..2
        int rr = k & 255;
        v = thetas[((g * 3 + kc) * 256 + rr) * 256 + j];
    }
    WT[idx] = f2bf(v);
}

// bsum[c'] = bs[g*256+j] + cbs[g*256+j] in permuted column order
__global__ void build_bsum(const float* __restrict__ bs, const float* __restrict__ cbs,
                           float* __restrict__ bsum) {
    int c = blockIdx.x * 256 + threadIdx.x;
    if (c >= 1024) return;
    int g = (c >> 4) & 3;
    int j = (c >> 6) * 16 + (c & 15);
    bsum[c] = bs[g * 256 + j] + cbs[g * 256 + j];
}

// ---------------- prop: wave-per-node edge gather ----------------
// out_bf[n,:] = bf16( scale * sum_e w[e]*xin[src[e],:]  - (sub? sub[n,:] : 0) )
// Optionally converts X_t row to bf16 (fused X staging).
// Block = 256 threads = 4 waves, each wave owns one node; no barriers
// (per-wave LDS slice; same-wave LDS RAW ordered by compiler waitcnt).
__global__ __launch_bounds__(256) void prop_kernel(
        const u16* __restrict__ xin, const u16* __restrict__ sub, float scale,
        const int* __restrict__ row_ptr, const int* __restrict__ csr_src,
        const float* __restrict__ csr_w, u16* __restrict__ out_bf,
        const float* __restrict__ X, int t, u16* __restrict__ xt_out) {
    __shared__ int s_src[4][64];
    __shared__ float s_w[4][64];
    int wid = threadIdx.x >> 6, l = threadIdx.x & 63;
    int n = blockIdx.x * 4 + wid;
    int start = row_ptr[n], end = row_ptr[n + 1];
    float acc0 = 0.f, acc1 = 0.f, acc2 = 0.f, acc3 = 0.f;
    int fb = l * 4;  // this lane's 4 features
    for (int base = start; base < end; base += 64) {
        int chunk = min(64, end - base);
        if (l < chunk) {
            s_src[wid][l] = csr_src[base + l];
            s_w[wid][l] = csr_w[base + l];
        }
        #pragma unroll 4
        for (int i = 0; i < chunk; i++) {
            int s = s_src[wid][i];
            float wt = s_w[wid][i];
            ushort4 hv = *(const ushort4*)(xin + (size_t)s * F + fb);
            acc0 += wt * bf2f(hv.x);
            acc1 += wt * bf2f(hv.y);
            acc2 += wt * bf2f(hv.z);
            acc3 += wt * bf2f(hv.w);
        }
    }
    size_t o = (size_t)n * F + fb;
    float r0 = scale * acc0, r1 = scale * acc1, r2 = scale * acc2, r3 = scale * acc3;
    if (sub) {
        ushort4 sv = *(const ushort4*)(sub + o);
        r0 -= bf2f(sv.x); r1 -= bf2f(sv.y); r2 -= bf2f(sv.z); r3 -= bf2f(sv.w);
    }
    ushort4 ov;
    ov.x = f2bf(r0); ov.y = f2bf(r1); ov.z = f2bf(r2); ov.w = f2bf(r3);
    *(ushort4*)(out_bf + o) = ov;
    if (xt_out) {
        float4 xv = *(const float4*)(X + (size_t)n * XROWSTRIDE + (size_t)t * F + fb);
        ushort4 xo;
        xo.x = f2bf(xv.x); xo.y = f2bf(xv.y); xo.z = f2bf(xv.z); xo.w = f2bf(xv.w);
        *(ushort4*)(xt_out + o) = xo;
    }
}

// ---------------- fused bf16 MFMA GEMM + LSTM epilogue ----------------
// A[5120,1024] = [Xt | Hb | Tx1 | Tx2] (bf16, row stride 256)
// WT = B^T in permuted column order (n-major, k-contig)
// Epilogue: thread-local gates -> C,H (fp32), Hb_new (bf16)
#define GBM 128
#define GBN 128
#define GBK 64

__global__ __launch_bounds__(256) void mfma_gemm(
        const u16* __restrict__ Xt, const u16* __restrict__ Hb,
        const u16* __restrict__ T1, const u16* __restrict__ T2,
        const u16* __restrict__ WT, const float* __restrict__ bsum,
        float* __restrict__ Cst, float* __restrict__ Hout, u16* __restrict__ HbNew) {
    __shared__ alignas(16) u16 As[GBM * GBK];
    __shared__ alignas(16) u16 Bs[GBN * GBK];
    int tid = threadIdx.x;
    int w = tid >> 6, l = tid & 63;
    int m0 = blockIdx.x * GBM, n0 = blockIdx.y * GBN;
    int wm = (w >> 1) * 64, wn = (w & 1) * 64;

    // staging: chunk c covers LDS rows [c*8, c*8+8); lane l -> row c*8 + l/8.
    // rule #21: linear LDS dest + inverse-swizzled SOURCE col + swizzled READ.
    int srow = l >> 3;                // row & 7
    int scol = 8 * ((l & 7) ^ srow);  // source elem col for this lane's 16B

    f32x4 acc[4][4] = {};

    for (int k0 = 0; k0 < 1024; k0 += GBK) {
        int seg = k0 >> 8;
        const u16* ab = (seg == 0) ? Xt : (seg == 1) ? Hb : (seg == 2) ? T1 : T2;
        ab += (k0 & 255);
        const u16* bb = WT + k0;
        #pragma unroll
        for (int i = 0; i < 4; i++) {
            int c = i * 4 + w;
            int row = c * 8 + srow;
            __builtin_amdgcn_global_load_lds(
                (const __attribute__((address_space(1))) u32*)(ab + (size_t)(m0 + row) * F + scol),
                (__attribute__((address_space(3))) u32*)(As + c * 512), 16, 0, 0);
            __builtin_amdgcn_global_load_lds(
                (const __attribute__((address_space(1))) u32*)(bb + (size_t)(n0 + row) * 1024 + scol),
                (__attribute__((address_space(3))) u32*)(Bs + c * 512), 16, 0, 0);
        }
        __syncthreads();
        #pragma unroll
        for (int kk = 0; kk < 2; kk++) {
            int kr = kk * 32 + (l >> 4) * 8;
            bf16x8 af[4], bfr[4];
            #pragma unroll
            for (int mf = 0; mf < 4; mf++) {
                int r = wm + mf * 16 + (l & 15);
                af[mf] = *(const bf16x8*)(As + r * GBK + (kr ^ ((r & 7) << 3)));
            }
            #pragma unroll
            for (int nf = 0; nf < 4; nf++) {
                int r = wn + nf * 16 + (l & 15);
                bfr[nf] = *(const bf16x8*)(Bs + r * GBK + (kr ^ ((r & 7) << 3)));
            }
            #pragma unroll
            for (int mf = 0; mf < 4; mf++)
                #pragma unroll
                for (int nf = 0; nf < 4; nf++)
                    acc[mf][nf] = __builtin_amdgcn_mfma_f32_16x16x32_bf16(
                        af[mf], bfr[nf], acc[mf][nf], 0, 0, 0);
        }
        __syncthreads();
    }

    // LSTM epilogue. C/D layout: col = lane&15, row = (lane>>4)*4 + reg.
    // nf = gate (I,F,T,O); feature j = group*16 + cc, group = n0/64 + (w&1).
    int cr = (l >> 4) * 4, cc = l & 15;
    int feat = ((n0 >> 6) + (w & 1)) * 16 + cc;
    float bI = bsum[n0 + wn + 0  + cc];
    float bF = bsum[n0 + wn + 16 + cc];
    float bT = bsum[n0 + wn + 32 + cc];
    float bO = bsum[n0 + wn + 48 + cc];
    #pragma unroll
    for (int mf = 0; mf < 4; mf++) {
        #pragma unroll
        for (int r = 0; r < 4; r++) {
            int row = m0 + wm + mf * 16 + cr + r;
            size_t o = (size_t)row * F + feat;
            float I  = fsigmoid(acc[mf][0][r] + bI);
            float Fg = fsigmoid(acc[mf][1][r] + bF);
            float Tc = ftanh(acc[mf][2][r] + bT);
            float O  = fsigmoid(acc[mf][3][r] + bO);
            float c  = Fg * Cst[o] + I * Tc;
            Cst[o] = c;
            float h = O * ftanh(c);
            Hout[o] = h;
            HbNew[o] = f2bf(h);
        }
    }
}

// ---------------- launch ----------------

extern "C" void kernel_launch(void* const* d_in, const int* in_sizes, int n_in,
                              void* d_out, int out_size, void* d_ws, size_t ws_size,
                              hipStream_t stream) {
    const float* X   = (const float*)d_in[0];
    const float* ew  = (const float*)d_in[1];
    const float* Ws  = (const float*)d_in[2];
    const float* bs  = (const float*)d_in[3];
    const float* th  = (const float*)d_in[4];
    const float* cbs = (const float*)d_in[5];
    const int*   ei  = (const int*)d_in[6];
    const int* src = ei;
    const int* dst = ei + E_EDGES;

    float* H = (float*)d_out;               // N*F
    float* C = H + (size_t)N_NODES * F;     // N*F

    char* w = (char*)d_ws;
    size_t off = 0;
    auto alloc = [&](size_t bytes) {
        void* p = w + off;
        off += (bytes + 255) & ~(size_t)255;
        return p;
    };
    float* deg     = (float*)alloc(N_NODES * 4);
    int*   cnt     = (int*)  alloc(N_NODES * 4);
    int*   cursor  = (int*)  alloc(N_NODES * 4);
    int*   row_ptr = (int*)  alloc((N_NODES + 1) * 4);
    int*   csr_src = (int*)  alloc(E_EDGES * 4);
    float* csr_w   = (float*)alloc(E_EDGES * 4);
    u16*   WT      = (u16*)  alloc((size_t)1024 * 1024 * 2);
    float* bsum    = (float*)alloc(1024 * 4);
    u16*   Xtbf    = (u16*)  alloc((size_t)N_NODES * F * 2);
    u16*   Hb0     = (u16*)  alloc((size_t)N_NODES * F * 2);
    u16*   Hb1     = (u16*)  alloc((size_t)N_NODES * F * 2);
    u16*   Tx1bf   = (u16*)  alloc((size_t)N_NODES * F * 2);
    u16*   Tx2bf   = (u16*)  alloc((size_t)N_NODES * F * 2);

    hipMemsetAsync(d_out, 0, (size_t)2 * N_NODES * F * 4, stream);
    hipMemsetAsync(Hb0, 0, (size_t)N_NODES * F * 2, stream);
    hipMemsetAsync(deg, 0, N_NODES * 4, stream);
    hipMemsetAsync(cnt, 0, N_NODES * 4, stream);
    hipMemsetAsync(cursor, 0, N_NODES * 4, stream);

    int eb = E_EDGES / 256;
    deg_kernel<<<eb, 256, 0, stream>>>(ew, src, deg);
    dis_kernel<<<N_NODES / 256, 256, 0, stream>>>(deg);
    count_kernel<<<eb, 256, 0, stream>>>(dst, cnt);
    scan_kernel<<<1, 256, 0, stream>>>(cnt, row_ptr);
    fill_csr<<<eb, 256, 0, stream>>>(src, dst, ew, deg, row_ptr, cursor, csr_src, csr_w);
    build_wcatT<<<(1024 * 1024) / 256, 256, 0, stream>>>(Ws, th, WT);
    build_bsum<<<4, 256, 0, stream>>>(bs, cbs, bsum);

    dim3 ggrid(N_NODES / GBM, ND / GBN);
    for (int t = 0; t < TSTEPS; t++) {
        u16* Hrd = (t & 1) ? Hb1 : Hb0;
        u16* Hwr = (t & 1) ? Hb0 : Hb1;
        // Tx1 = L_hat @ H   (+ fused X_t -> bf16 conversion)
        prop_kernel<<<N_NODES / 4, 256, 0, stream>>>(Hrd, nullptr, 1.f, row_ptr, csr_src,
                                                     csr_w, Tx1bf, X, t, Xtbf);
        // Tx2 = 2 * (L_hat @ Tx1) - H
        prop_kernel<<<N_NODES / 4, 256, 0, stream>>>(Tx1bf, Hrd, 2.f, row_ptr, csr_src,
                                                     csr_w, Tx2bf, nullptr, 0, nullptr);
        // gates + LSTM pointwise fused
        mfma_gemm<<<ggrid, 256, 0, stream>>>(Xtbf, Hrd, Tx1bf, Tx2bf, WT, bsum, C, H, Hwr);
    }
}

// Round 4
// 1010.097 us; speedup vs baseline: 4.8457x; 1.1687x over previous
//
#include <hip/hip_runtime.h>
#include <cstddef>
#include <cstdint>

#define N_NODES 5120
#define E_EDGES 163840
#define F 256
#define TSTEPS 24
#define ND 1024          // GEMM N = 4*256 (gates, column-permuted)
#define XROWSTRIDE 6144  // T*F

typedef unsigned short u16;
typedef unsigned int u32;
typedef __bf16 bf16x8 __attribute__((ext_vector_type(8)));
typedef float f32x4 __attribute__((ext_vector_type(4)));

__device__ __forceinline__ u16 f2bf(float f) {
    u32 u = __float_as_uint(f);
    u = (u + 0x7FFFu + ((u >> 16) & 1u)) >> 16;  // round-to-nearest-even
    return (u16)u;
}
__device__ __forceinline__ float bf2f(u16 h) {
    return __uint_as_float((u32)h << 16);
}
__device__ __forceinline__ float fsigmoid(float x) {
    return 1.f / (1.f + __expf(-x));
}
__device__ __forceinline__ float ftanh(float x) {
    // tanh(x) = 1 - 2/(exp(2x)+1); saturates correctly for |x| large
    return 1.f - 2.f / (__expf(2.f * x) + 1.f);
}

// ---------------- graph preprocessing ----------------

__global__ void deg_kernel(const float* __restrict__ ew, const int* __restrict__ src,
                           float* __restrict__ deg) {
    int e = blockIdx.x * 256 + threadIdx.x;
    if (e < E_EDGES) atomicAdd(&deg[src[e]], ew[e]);
}

__global__ void dis_kernel(float* __restrict__ deg) {
    int n = blockIdx.x * 256 + threadIdx.x;
    if (n < N_NODES) {
        float d = deg[n];
        deg[n] = d > 0.f ? rsqrtf(d) : 0.f;
    }
}

__global__ void count_kernel(const int* __restrict__ dst, int* __restrict__ cnt) {
    int e = blockIdx.x * 256 + threadIdx.x;
    if (e < E_EDGES) atomicAdd(&cnt[dst[e]], 1);
}

// one block, 256 threads, 20 counts each (N_NODES = 256*20)
__global__ void scan_kernel(const int* __restrict__ cnt, int* __restrict__ row_ptr) {
    __shared__ int s[256];
    int tid = threadIdx.x;
    int base = tid * 20;
    int local[20];
    int sum = 0;
    #pragma unroll
    for (int i = 0; i < 20; i++) { local[i] = sum; sum += cnt[base + i]; }
    s[tid] = sum;
    __syncthreads();
    for (int off = 1; off < 256; off <<= 1) {
        int v = (tid >= off) ? s[tid - off] : 0;
        __syncthreads();
        s[tid] += v;
        __syncthreads();
    }
    int offset = (tid == 0) ? 0 : s[tid - 1];
    #pragma unroll
    for (int i = 0; i < 20; i++) row_ptr[base + i] = offset + local[i];
    if (tid == 0) row_ptr[N_NODES] = E_EDGES;
}

__global__ void fill_csr(const int* __restrict__ src, const int* __restrict__ dst,
                         const float* __restrict__ ew, const float* __restrict__ dis,
                         const int* __restrict__ row_ptr, int* __restrict__ cursor,
                         int* __restrict__ csr_src, float* __restrict__ csr_w) {
    int e = blockIdx.x * 256 + threadIdx.x;
    if (e >= E_EDGES) return;
    int s = src[e], d = dst[e];
    int pos = row_ptr[d] + atomicAdd(&cursor[d], 1);
    csr_src[pos] = s;
    // w_hat = (2/lambda_max)*(-dis[src]*w*dis[dst]); lambda_max=2 -> factor 1
    csr_w[pos] = -dis[s] * ew[e] * dis[d];
}

// Column permutation: col'(g, j) = (j>>4)*64 + g*16 + (j&15).
// Inverse: g = (c>>4)&3, j = (c>>6)*16 + (c&15).
// WT[c'][k] (bf16, k contiguous) = Wcat[k][g*256+j]
__global__ void build_wcatT(const float* __restrict__ Ws, const float* __restrict__ thetas,
                            u16* __restrict__ WT) {
    int idx = blockIdx.x * 256 + threadIdx.x;
    if (idx >= 1024 * 1024) return;
    int c = idx >> 10, k = idx & 1023;
    int g = (c >> 4) & 3;
    int j = (c >> 6) * 16 + (c & 15);
    float v;
    if (k < 256) {
        v = Ws[(g * 256 + k) * 256 + j];
    } else {
        int kc = (k >> 8) - 1;  // 0..2
        int rr = k & 255;
        v = thetas[((g * 3 + kc) * 256 + rr) * 256 + j];
    }
    WT[idx] = f2bf(v);
}

// bsum[c'] = bs[g*256+j] + cbs[g*256+j] in permuted column order
__global__ void build_bsum(const float* __restrict__ bs, const float* __restrict__ cbs,
                           float* __restrict__ bsum) {
    int c = blockIdx.x * 256 + threadIdx.x;
    if (c >= 1024) return;
    int g = (c >> 4) & 3;
    int j = (c >> 6) * 16 + (c & 15);
    bsum[c] = bs[g * 256 + j] + cbs[g * 256 + j];
}

// ---------------- prop: wave-per-node edge gather ----------------

__global__ __launch_bounds__(256) void prop_kernel(
        const u16* __restrict__ xin, const u16* __restrict__ sub, float scale,
        const int* __restrict__ row_ptr, const int* __restrict__ csr_src,
        const float* __restrict__ csr_w, u16* __restrict__ out_bf,
        const float* __restrict__ X, int t, u16* __restrict__ xt_out) {
    __shared__ int s_src[4][64];
    __shared__ float s_w[4][64];
    int wid = threadIdx.x >> 6, l = threadIdx.x & 63;
    int n = blockIdx.x * 4 + wid;
    int start = row_ptr[n], end = row_ptr[n + 1];
    float acc0 = 0.f, acc1 = 0.f, acc2 = 0.f, acc3 = 0.f;
    int fb = l * 4;  // this lane's 4 features
    for (int base = start; base < end; base += 64) {
        int chunk = min(64, end - base);
        if (l < chunk) {
            s_src[wid][l] = csr_src[base + l];
            s_w[wid][l] = csr_w[base + l];
        }
        #pragma unroll 4
        for (int i = 0; i < chunk; i++) {
            int s = s_src[wid][i];
            float wt = s_w[wid][i];
            ushort4 hv = *(const ushort4*)(xin + (size_t)s * F + fb);
            acc0 += wt * bf2f(hv.x);
            acc1 += wt * bf2f(hv.y);
            acc2 += wt * bf2f(hv.z);
            acc3 += wt * bf2f(hv.w);
        }
    }
    size_t o = (size_t)n * F + fb;
    float r0 = scale * acc0, r1 = scale * acc1, r2 = scale * acc2, r3 = scale * acc3;
    if (sub) {
        ushort4 sv = *(const ushort4*)(sub + o);
        r0 -= bf2f(sv.x); r1 -= bf2f(sv.y); r2 -= bf2f(sv.z); r3 -= bf2f(sv.w);
    }
    ushort4 ov;
    ov.x = f2bf(r0); ov.y = f2bf(r1); ov.z = f2bf(r2); ov.w = f2bf(r3);
    *(ushort4*)(out_bf + o) = ov;
    if (xt_out) {
        float4 xv = *(const float4*)(X + (size_t)n * XROWSTRIDE + (size_t)t * F + fb);
        ushort4 xo;
        xo.x = f2bf(xv.x); xo.y = f2bf(xv.y); xo.z = f2bf(xv.z); xo.w = f2bf(xv.w);
        *(ushort4*)(xt_out + o) = xo;
    }
}

// ---------------- fused bf16 MFMA GEMM + LSTM epilogue ----------------
// Tile 64x128 -> grid 80x8 = 640 blocks (2.5 blocks/CU for latency hiding).
// A[5120,1024] = [Xt | Hb | Tx1 | Tx2] (bf16, row stride 256)
// WT = B^T in permuted column order (n-major, k-contig)
#define GBM 64
#define GBN 128
#define GBK 64

__global__ __launch_bounds__(256) void mfma_gemm(
        const u16* __restrict__ Xt, const u16* __restrict__ Hb,
        const u16* __restrict__ T1, const u16* __restrict__ T2,
        const u16* __restrict__ WT, const float* __restrict__ bsum,
        float* __restrict__ Cst, float* __restrict__ Hout, u16* __restrict__ HbNew,
        int writeH) {
    __shared__ alignas(16) u16 As[GBM * GBK];
    __shared__ alignas(16) u16 Bs[GBN * GBK];
    int tid = threadIdx.x;
    int w = tid >> 6, l = tid & 63;
    int m0 = blockIdx.x * GBM, n0 = blockIdx.y * GBN;
    int wm = (w >> 1) * 32, wn = (w & 1) * 64;   // wave sub-tile 32x64

    // staging: chunk c covers LDS rows [c*8, c*8+8); lane l -> row c*8 + l/8.
    // rule #21: linear LDS dest + inverse-swizzled SOURCE col + swizzled READ.
    int srow = l >> 3;                // row & 7
    int scol = 8 * ((l & 7) ^ srow);  // source elem col for this lane's 16B

    f32x4 acc[2][4] = {};

    for (int k0 = 0; k0 < 1024; k0 += GBK) {
        int seg = k0 >> 8;
        const u16* ab = (seg == 0) ? Xt : (seg == 1) ? Hb : (seg == 2) ? T1 : T2;
        ab += (k0 & 255);
        const u16* bb = WT + k0;
        // A: 64 rows = 8 chunks (2 per wave)
        #pragma unroll
        for (int i = 0; i < 2; i++) {
            int c = i * 4 + w;
            int row = c * 8 + srow;
            __builtin_amdgcn_global_load_lds(
                (const __attribute__((address_space(1))) u32*)(ab + (size_t)(m0 + row) * F + scol),
                (__attribute__((address_space(3))) u32*)(As + c * 512), 16, 0, 0);
        }
        // B: 128 rows = 16 chunks (4 per wave)
        #pragma unroll
        for (int i = 0; i < 4; i++) {
            int c = i * 4 + w;
            int row = c * 8 + srow;
            __builtin_amdgcn_global_load_lds(
                (const __attribute__((address_space(1))) u32*)(bb + (size_t)(n0 + row) * 1024 + scol),
                (__attribute__((address_space(3))) u32*)(Bs + c * 512), 16, 0, 0);
        }
        __syncthreads();
        #pragma unroll
        for (int kk = 0; kk < 2; kk++) {
            int kr = kk * 32 + (l >> 4) * 8;
            bf16x8 af[2], bfr[4];
            #pragma unroll
            for (int mf = 0; mf < 2; mf++) {
                int r = wm + mf * 16 + (l & 15);
                af[mf] = *(const bf16x8*)(As + r * GBK + (kr ^ ((r & 7) << 3)));
            }
            #pragma unroll
            for (int nf = 0; nf < 4; nf++) {
                int r = wn + nf * 16 + (l & 15);
                bfr[nf] = *(const bf16x8*)(Bs + r * GBK + (kr ^ ((r & 7) << 3)));
            }
            #pragma unroll
            for (int mf = 0; mf < 2; mf++)
                #pragma unroll
                for (int nf = 0; nf < 4; nf++)
                    acc[mf][nf] = __builtin_amdgcn_mfma_f32_16x16x32_bf16(
                        af[mf], bfr[nf], acc[mf][nf], 0, 0, 0);
        }
        __syncthreads();
    }

    // LSTM epilogue. C/D layout: col = lane&15, row = (lane>>4)*4 + reg.
    // nf = gate (I,F,T,O); feature j = group*16 + cc, group = n0/64 + (w&1).
    int cr = (l >> 4) * 4, cc = l & 15;
    int feat = ((n0 >> 6) + (w & 1)) * 16 + cc;
    float bI = bsum[n0 + wn + 0  + cc];
    float bF = bsum[n0 + wn + 16 + cc];
    float bT = bsum[n0 + wn + 32 + cc];
    float bO = bsum[n0 + wn + 48 + cc];
    #pragma unroll
    for (int mf = 0; mf < 2; mf++) {
        #pragma unroll
        for (int r = 0; r < 4; r++) {
            int row = m0 + wm + mf * 16 + cr + r;
            size_t o = (size_t)row * F + feat;
            float I  = fsigmoid(acc[mf][0][r] + bI);
            float Fg = fsigmoid(acc[mf][1][r] + bF);
            float Tc = ftanh(acc[mf][2][r] + bT);
            float O  = fsigmoid(acc[mf][3][r] + bO);
            float c  = Fg * Cst[o] + I * Tc;
            Cst[o] = c;
            float h = O * ftanh(c);
            if (writeH) Hout[o] = h;   // fp32 H only needed at the final step
            HbNew[o] = f2bf(h);
        }
    }
}

// ---------------- launch ----------------

extern "C" void kernel_launch(void* const* d_in, const int* in_sizes, int n_in,
                              void* d_out, int out_size, void* d_ws, size_t ws_size,
                              hipStream_t stream) {
    const float* X   = (const float*)d_in[0];
    const float* ew  = (const float*)d_in[1];
    const float* Ws  = (const float*)d_in[2];
    const float* bs  = (const float*)d_in[3];
    const float* th  = (const float*)d_in[4];
    const float* cbs = (const float*)d_in[5];
    const int*   ei  = (const int*)d_in[6];
    const int* src = ei;
    const int* dst = ei + E_EDGES;

    float* H = (float*)d_out;               // N*F
    float* C = H + (size_t)N_NODES * F;     // N*F

    char* w = (char*)d_ws;
    size_t off = 0;
    auto alloc = [&](size_t bytes) {
        void* p = w + off;
        off += (bytes + 255) & ~(size_t)255;
        return p;
    };
    float* deg     = (float*)alloc(N_NODES * 4);
    int*   cnt     = (int*)  alloc(N_NODES * 4);
    int*   cursor  = (int*)  alloc(N_NODES * 4);
    int*   row_ptr = (int*)  alloc((N_NODES + 1) * 4);
    int*   csr_src = (int*)  alloc(E_EDGES * 4);
    float* csr_w   = (float*)alloc(E_EDGES * 4);
    u16*   WT      = (u16*)  alloc((size_t)1024 * 1024 * 2);
    float* bsum    = (float*)alloc(1024 * 4);
    u16*   Xtbf    = (u16*)  alloc((size_t)N_NODES * F * 2);
    u16*   Hb0     = (u16*)  alloc((size_t)N_NODES * F * 2);
    u16*   Hb1     = (u16*)  alloc((size_t)N_NODES * F * 2);
    u16*   Tx1bf   = (u16*)  alloc((size_t)N_NODES * F * 2);
    u16*   Tx2bf   = (u16*)  alloc((size_t)N_NODES * F * 2);

    hipMemsetAsync(d_out, 0, (size_t)2 * N_NODES * F * 4, stream);
    hipMemsetAsync(Hb0, 0, (size_t)N_NODES * F * 2, stream);
    hipMemsetAsync(deg, 0, N_NODES * 4, stream);
    hipMemsetAsync(cnt, 0, N_NODES * 4, stream);
    hipMemsetAsync(cursor, 0, N_NODES * 4, stream);

    int eb = E_EDGES / 256;
    deg_kernel<<<eb, 256, 0, stream>>>(ew, src, deg);
    dis_kernel<<<N_NODES / 256, 256, 0, stream>>>(deg);
    count_kernel<<<eb, 256, 0, stream>>>(dst, cnt);
    scan_kernel<<<1, 256, 0, stream>>>(cnt, row_ptr);
    fill_csr<<<eb, 256, 0, stream>>>(src, dst, ew, deg, row_ptr, cursor, csr_src, csr_w);
    build_wcatT<<<(1024 * 1024) / 256, 256, 0, stream>>>(Ws, th, WT);
    build_bsum<<<4, 256, 0, stream>>>(bs, cbs, bsum);

    dim3 ggrid(N_NODES / GBM, ND / GBN);
    for (int t = 0; t < TSTEPS; t++) {
        u16* Hrd = (t & 1) ? Hb1 : Hb0;
        u16* Hwr = (t & 1) ? Hb0 : Hb1;
        // Tx1 = L_hat @ H   (+ fused X_t -> bf16 conversion)
        prop_kernel<<<N_NODES / 4, 256, 0, stream>>>(Hrd, nullptr, 1.f, row_ptr, csr_src,
                                                     csr_w, Tx1bf, X, t, Xtbf);
        // Tx2 = 2 * (L_hat @ Tx1) - H
        prop_kernel<<<N_NODES / 4, 256, 0, stream>>>(Tx1bf, Hrd, 2.f, row_ptr, csr_src,
                                                     csr_w, Tx2bf, nullptr, 0, nullptr);
        // gates + LSTM pointwise fused
        mfma_gemm<<<ggrid, 256, 0, stream>>>(Xtbf, Hrd, Tx1bf, Tx2bf, WT, bsum, C, H, Hwr,
                                             t == TSTEPS - 1 ? 1 : 0);
    }
}